// Round 1
// baseline (887.029 us; speedup 1.0000x reference)
//
#include <hip/hip_runtime.h>

#define EMB 64

// ---------------- kernel 1: total = sum(edge_weight) ----------------
__global__ void sum_weights_kernel(const float* __restrict__ w, int n,
                                   float* __restrict__ total) {
    int gid = blockIdx.x * blockDim.x + threadIdx.x;
    int stride = gridDim.x * blockDim.x;
    float s = 0.f;
    for (int i = gid; i < n; i += stride) s += w[i];
    // wave-64 reduction
    #pragma unroll
    for (int off = 32; off > 0; off >>= 1) s += __shfl_down(s, off, 64);
    if ((threadIdx.x & 63) == 0) atomicAdd(total, s);
}

// ---------------- kernel 2: scatter-add conv_output ----------------
// one wave per edge: lane d handles dim d. conv (== d_out) must be pre-zeroed.
__global__ void edge_scatter_kernel(const int* __restrict__ idx,
                                    const float* __restrict__ w,
                                    const float* __restrict__ left,
                                    const float* __restrict__ total,
                                    float* __restrict__ conv,
                                    long long n_threads) {
    long long gid = (long long)blockIdx.x * blockDim.x + threadIdx.x;
    if (gid >= n_threads) return;
    int e = (int)(gid >> 6);
    int d = (int)(gid & 63);
    float inv = 1.0f / fmaxf(total[0], 1.0f);
    int row = idx[2 * e];       // wave-uniform load
    int col = idx[2 * e + 1];   // wave-uniform load
    float v = w[e] * inv;       // wave-uniform load
    float msg = left[(size_t)col * EMB + d] * v;   // 256B coalesced gather
    atomicAdd(&conv[(size_t)row * EMB + d], msg);  // 256B coalesced atomic
}

// ---------------- kernel 3: fused  h = right + t*(c - conv); MLP ----------------
// one thread per row; reads conv row from `io` (== d_out) and overwrites it
// in place with the final output (thread-local row -> race-free).
__global__ __launch_bounds__(256, 1) void mlp_kernel(
    const float* __restrict__ right, const float* __restrict__ c,
    const float* __restrict__ temp,
    const float* __restrict__ W1, const float* __restrict__ b1,
    const float* __restrict__ W2, const float* __restrict__ b2,
    float* __restrict__ io, int n) {
    int r = blockIdx.x * blockDim.x + threadIdx.x;
    if (r >= n) return;
    float t1 = temp[1];
    float cv = c[r];

    float h[EMB];
    const float4* rp = (const float4*)(right + (size_t)r * EMB);
    const float4* qp = (const float4*)(io + (size_t)r * EMB);
    #pragma unroll
    for (int q = 0; q < EMB / 4; ++q) {
        float4 rv = rp[q];
        float4 qv = qp[q];
        h[4 * q + 0] = rv.x + t1 * (cv - qv.x);
        h[4 * q + 1] = rv.y + t1 * (cv - qv.y);
        h[4 * q + 2] = rv.z + t1 * (cv - qv.z);
        h[4 * q + 3] = rv.w + t1 * (cv - qv.w);
    }

    float h1[EMB];
    #pragma unroll
    for (int j = 0; j < EMB; j += 4) {
        float s0 = b1[j + 0], s1 = b1[j + 1], s2 = b1[j + 2], s3 = b1[j + 3];
        #pragma unroll
        for (int k = 0; k < EMB; ++k) {
            float hk = h[k];
            s0 = fmaf(hk, W1[(j + 0) * EMB + k], s0);  // wave-uniform -> s_load
            s1 = fmaf(hk, W1[(j + 1) * EMB + k], s1);
            s2 = fmaf(hk, W1[(j + 2) * EMB + k], s2);
            s3 = fmaf(hk, W1[(j + 3) * EMB + k], s3);
        }
        h1[j + 0] = fmaxf(s0, 0.f);
        h1[j + 1] = fmaxf(s1, 0.f);
        h1[j + 2] = fmaxf(s2, 0.f);
        h1[j + 3] = fmaxf(s3, 0.f);
    }

    float4* op = (float4*)(io + (size_t)r * EMB);
    #pragma unroll
    for (int j = 0; j < EMB; j += 4) {
        float s0 = b2[j + 0], s1 = b2[j + 1], s2 = b2[j + 2], s3 = b2[j + 3];
        #pragma unroll
        for (int k = 0; k < EMB; ++k) {
            float hk = h1[k];
            s0 = fmaf(hk, W2[(j + 0) * EMB + k], s0);
            s1 = fmaf(hk, W2[(j + 1) * EMB + k], s1);
            s2 = fmaf(hk, W2[(j + 2) * EMB + k], s2);
            s3 = fmaf(hk, W2[(j + 3) * EMB + k], s3);
        }
        op[j / 4] = make_float4(s0, s1, s2, s3);
    }
}

extern "C" void kernel_launch(void* const* d_in, const int* in_sizes, int n_in,
                              void* d_out, int out_size, void* d_ws, size_t ws_size,
                              hipStream_t stream) {
    const float* left   = (const float*)d_in[0];   // (N_LEFT, 64)
    // d_in[1] = right_features_k  (unused by reference)
    const int*   eidx   = (const int*)d_in[2];     // (N_EDGES, 2)
    const float* ew     = (const float*)d_in[3];   // (N_EDGES,)
    const float* right  = (const float*)d_in[4];   // (N_RIGHT, 64)
    const float* c      = (const float*)d_in[5];   // (N_RIGHT, 1)
    // d_in[6] = b (unused by reference)
    const float* temp   = (const float*)d_in[7];   // (2,)
    const float* W1     = (const float*)d_in[8];   // (64,64)
    const float* b1     = (const float*)d_in[9];   // (64,)
    const float* W2     = (const float*)d_in[10];  // (64,64)
    const float* b2     = (const float*)d_in[11];  // (64,)

    const int n_edges = in_sizes[3];
    const int n_right = in_sizes[4] / EMB;
    float* out = (float*)d_out;
    float* total = (float*)d_ws;

    // zero the accumulator (d_out doubles as conv_output) and the total
    hipMemsetAsync(d_out, 0, (size_t)out_size * sizeof(float), stream);
    hipMemsetAsync(d_ws, 0, sizeof(float), stream);

    // 1) total = sum(edge_weight)
    {
        int blocks = 2048;
        sum_weights_kernel<<<blocks, 256, 0, stream>>>(ew, n_edges, total);
    }

    // 2) scatter-add: one wave per edge
    {
        long long n_threads = (long long)n_edges * EMB;
        long long blocks = (n_threads + 255) / 256;
        edge_scatter_kernel<<<(int)blocks, 256, 0, stream>>>(
            eidx, ew, left, total, out, n_threads);
    }

    // 3) fused h/MLP, in-place on d_out
    {
        int blocks = (n_right + 255) / 256;
        mlp_kernel<<<blocks, 256, 0, stream>>>(right, c, temp, W1, b1, W2, b2,
                                               out, n_right);
    }
}

// Round 2
// 804.114 us; speedup vs baseline: 1.1031x; 1.1031x over previous
//
#include <hip/hip_runtime.h>

#define EMB 64

// ===================== sort-based path =====================

// K1: hist[row]++ over edges, and total = sum(edge_weight)
__global__ void hist_total_kernel(const int* __restrict__ idx,
                                  const float* __restrict__ w, int n_edges,
                                  int* __restrict__ hist,
                                  float* __restrict__ total) {
    int gid = blockIdx.x * blockDim.x + threadIdx.x;
    int stride = gridDim.x * blockDim.x;
    float s = 0.f;
    for (int e = gid; e < n_edges; e += stride) {
        s += w[e];
        atomicAdd(&hist[idx[2 * e]], 1);
    }
    #pragma unroll
    for (int off = 32; off > 0; off >>= 1) s += __shfl_down(s, off, 64);
    if ((threadIdx.x & 63) == 0) atomicAdd(total, s);
}

// K2: single-block exclusive scan, in place (counts -> offsets)
__global__ __launch_bounds__(1024, 1) void scan_kernel(int* __restrict__ data, int n) {
    __shared__ int sums[1024];
    int t = threadIdx.x;
    int C = (n + 1023) >> 10;
    int lo = t * C;
    int hi = min(lo + C, n);
    int s = 0;
    for (int i = lo; i < hi; ++i) s += data[i];
    sums[t] = s;
    __syncthreads();
    // Hillis-Steele inclusive scan
    for (int off = 1; off < 1024; off <<= 1) {
        int v = (t >= off) ? sums[t - off] : 0;
        __syncthreads();
        sums[t] += v;
        __syncthreads();
    }
    int run = (t == 0) ? 0 : sums[t - 1];
    for (int i = lo; i < hi; ++i) {
        int v = data[i];
        data[i] = run;
        run += v;
    }
}

// K3: scatter (col, w) into row-sorted order. offs[r] becomes segment END.
__global__ void scatter_kernel(const int* __restrict__ idx,
                               const float* __restrict__ w, int n_edges,
                               int* __restrict__ offs,
                               int2* __restrict__ sorted) {
    int gid = blockIdx.x * blockDim.x + threadIdx.x;
    int stride = gridDim.x * blockDim.x;
    for (int e = gid; e < n_edges; e += stride) {
        int row = idx[2 * e];
        int col = idx[2 * e + 1];
        float v = w[e];
        int pos = atomicAdd(&offs[row], 1);
        sorted[pos] = make_int2(col, __float_as_int(v));
    }
}

// K4: one wave per row: conv = sum(w*left[col]); h = right + t1*(c - conv/total)
__global__ void seg_gather_kernel(const int2* __restrict__ sorted,
                                  const int* __restrict__ offs,
                                  const float* __restrict__ left,
                                  const float* __restrict__ right,
                                  const float* __restrict__ c,
                                  const float* __restrict__ temp,
                                  const float* __restrict__ total,
                                  float* __restrict__ hout, int n_right) {
    int gid = blockIdx.x * blockDim.x + threadIdx.x;
    int wid = gid >> 6;
    int lane = gid & 63;
    if (wid >= n_right) return;
    int end = offs[wid];
    int start = (wid == 0) ? 0 : offs[wid - 1];

    float a0 = 0.f, a1 = 0.f, a2 = 0.f, a3 = 0.f;
    int e = start;
    for (; e + 4 <= end; e += 4) {
        int2 c0 = sorted[e + 0];
        int2 c1 = sorted[e + 1];
        int2 c2 = sorted[e + 2];
        int2 c3 = sorted[e + 3];
        a0 = fmaf(__int_as_float(c0.y), left[(size_t)c0.x * EMB + lane], a0);
        a1 = fmaf(__int_as_float(c1.y), left[(size_t)c1.x * EMB + lane], a1);
        a2 = fmaf(__int_as_float(c2.y), left[(size_t)c2.x * EMB + lane], a2);
        a3 = fmaf(__int_as_float(c3.y), left[(size_t)c3.x * EMB + lane], a3);
    }
    for (; e < end; ++e) {
        int2 cc = sorted[e];
        a0 = fmaf(__int_as_float(cc.y), left[(size_t)cc.x * EMB + lane], a0);
    }
    float conv = (a0 + a1) + (a2 + a3);
    float inv = 1.0f / fmaxf(total[0], 1.0f);
    float t1 = temp[1];
    float h = right[(size_t)wid * EMB + lane] + t1 * (c[wid] - conv * inv);
    hout[(size_t)wid * EMB + lane] = h;
}

// K5: MLP on h (in place in io): out = relu(h@W1^T+b1)@W2^T+b2
__global__ __launch_bounds__(256, 1) void mlp_kernel(
    const float* __restrict__ W1, const float* __restrict__ b1,
    const float* __restrict__ W2, const float* __restrict__ b2,
    float* __restrict__ io, int n) {
    int r = blockIdx.x * blockDim.x + threadIdx.x;
    if (r >= n) return;

    float h[EMB];
    const float4* qp = (const float4*)(io + (size_t)r * EMB);
    #pragma unroll
    for (int q = 0; q < EMB / 4; ++q) {
        float4 qv = qp[q];
        h[4 * q + 0] = qv.x;
        h[4 * q + 1] = qv.y;
        h[4 * q + 2] = qv.z;
        h[4 * q + 3] = qv.w;
    }

    float h1[EMB];
    #pragma unroll
    for (int j = 0; j < EMB; j += 4) {
        float s0 = b1[j + 0], s1 = b1[j + 1], s2 = b1[j + 2], s3 = b1[j + 3];
        #pragma unroll
        for (int k = 0; k < EMB; ++k) {
            float hk = h[k];
            s0 = fmaf(hk, W1[(j + 0) * EMB + k], s0);
            s1 = fmaf(hk, W1[(j + 1) * EMB + k], s1);
            s2 = fmaf(hk, W1[(j + 2) * EMB + k], s2);
            s3 = fmaf(hk, W1[(j + 3) * EMB + k], s3);
        }
        h1[j + 0] = fmaxf(s0, 0.f);
        h1[j + 1] = fmaxf(s1, 0.f);
        h1[j + 2] = fmaxf(s2, 0.f);
        h1[j + 3] = fmaxf(s3, 0.f);
    }

    float4* op = (float4*)(io + (size_t)r * EMB);
    #pragma unroll
    for (int j = 0; j < EMB; j += 4) {
        float s0 = b2[j + 0], s1 = b2[j + 1], s2 = b2[j + 2], s3 = b2[j + 3];
        #pragma unroll
        for (int k = 0; k < EMB; ++k) {
            float hk = h1[k];
            s0 = fmaf(hk, W2[(j + 0) * EMB + k], s0);
            s1 = fmaf(hk, W2[(j + 1) * EMB + k], s1);
            s2 = fmaf(hk, W2[(j + 2) * EMB + k], s2);
            s3 = fmaf(hk, W2[(j + 3) * EMB + k], s3);
        }
        op[j / 4] = make_float4(s0, s1, s2, s3);
    }
}

// ===================== fallback (round-1 atomic path) =====================

__global__ void sum_weights_kernel(const float* __restrict__ w, int n,
                                   float* __restrict__ total) {
    int gid = blockIdx.x * blockDim.x + threadIdx.x;
    int stride = gridDim.x * blockDim.x;
    float s = 0.f;
    for (int i = gid; i < n; i += stride) s += w[i];
    #pragma unroll
    for (int off = 32; off > 0; off >>= 1) s += __shfl_down(s, off, 64);
    if ((threadIdx.x & 63) == 0) atomicAdd(total, s);
}

__global__ void edge_scatter_kernel(const int* __restrict__ idx,
                                    const float* __restrict__ w,
                                    const float* __restrict__ left,
                                    const float* __restrict__ total,
                                    float* __restrict__ conv,
                                    long long n_threads) {
    long long gid = (long long)blockIdx.x * blockDim.x + threadIdx.x;
    if (gid >= n_threads) return;
    int e = (int)(gid >> 6);
    int d = (int)(gid & 63);
    float inv = 1.0f / fmaxf(total[0], 1.0f);
    int row = idx[2 * e];
    int col = idx[2 * e + 1];
    float v = w[e] * inv;
    float msg = left[(size_t)col * EMB + d] * v;
    atomicAdd(&conv[(size_t)row * EMB + d], msg);
}

__global__ __launch_bounds__(256, 1) void fused_mlp_kernel(
    const float* __restrict__ right, const float* __restrict__ c,
    const float* __restrict__ temp,
    const float* __restrict__ W1, const float* __restrict__ b1,
    const float* __restrict__ W2, const float* __restrict__ b2,
    float* __restrict__ io, int n) {
    int r = blockIdx.x * blockDim.x + threadIdx.x;
    if (r >= n) return;
    float t1 = temp[1];
    float cv = c[r];
    float h[EMB];
    const float4* rp = (const float4*)(right + (size_t)r * EMB);
    const float4* qp = (const float4*)(io + (size_t)r * EMB);
    #pragma unroll
    for (int q = 0; q < EMB / 4; ++q) {
        float4 rv = rp[q];
        float4 qv = qp[q];
        h[4 * q + 0] = rv.x + t1 * (cv - qv.x);
        h[4 * q + 1] = rv.y + t1 * (cv - qv.y);
        h[4 * q + 2] = rv.z + t1 * (cv - qv.z);
        h[4 * q + 3] = rv.w + t1 * (cv - qv.w);
    }
    float h1[EMB];
    #pragma unroll
    for (int j = 0; j < EMB; j += 4) {
        float s0 = b1[j], s1 = b1[j + 1], s2 = b1[j + 2], s3 = b1[j + 3];
        #pragma unroll
        for (int k = 0; k < EMB; ++k) {
            float hk = h[k];
            s0 = fmaf(hk, W1[(j + 0) * EMB + k], s0);
            s1 = fmaf(hk, W1[(j + 1) * EMB + k], s1);
            s2 = fmaf(hk, W1[(j + 2) * EMB + k], s2);
            s3 = fmaf(hk, W1[(j + 3) * EMB + k], s3);
        }
        h1[j] = fmaxf(s0, 0.f);
        h1[j + 1] = fmaxf(s1, 0.f);
        h1[j + 2] = fmaxf(s2, 0.f);
        h1[j + 3] = fmaxf(s3, 0.f);
    }
    float4* op = (float4*)(io + (size_t)r * EMB);
    #pragma unroll
    for (int j = 0; j < EMB; j += 4) {
        float s0 = b2[j], s1 = b2[j + 1], s2 = b2[j + 2], s3 = b2[j + 3];
        #pragma unroll
        for (int k = 0; k < EMB; ++k) {
            float hk = h1[k];
            s0 = fmaf(hk, W2[(j + 0) * EMB + k], s0);
            s1 = fmaf(hk, W2[(j + 1) * EMB + k], s1);
            s2 = fmaf(hk, W2[(j + 2) * EMB + k], s2);
            s3 = fmaf(hk, W2[(j + 3) * EMB + k], s3);
        }
        op[j / 4] = make_float4(s0, s1, s2, s3);
    }
}

// ===================== launch =====================

extern "C" void kernel_launch(void* const* d_in, const int* in_sizes, int n_in,
                              void* d_out, int out_size, void* d_ws, size_t ws_size,
                              hipStream_t stream) {
    const float* left   = (const float*)d_in[0];
    const int*   eidx   = (const int*)d_in[2];
    const float* ew     = (const float*)d_in[3];
    const float* right  = (const float*)d_in[4];
    const float* c      = (const float*)d_in[5];
    const float* temp   = (const float*)d_in[7];
    const float* W1     = (const float*)d_in[8];
    const float* b1     = (const float*)d_in[9];
    const float* W2     = (const float*)d_in[10];
    const float* b2     = (const float*)d_in[11];

    const int n_edges = in_sizes[3];
    const int n_right = in_sizes[4] / EMB;
    float* out = (float*)d_out;

    // ws layout: [0..4) total | [64 .. 64+4*n_right) offs | aligned | sorted int2[n_edges]
    size_t offs_off = 64;
    size_t offs_bytes = (size_t)n_right * sizeof(int);
    size_t sorted_off = (offs_off + offs_bytes + 255) & ~(size_t)255;
    size_t required = sorted_off + (size_t)n_edges * sizeof(int2);

    if (ws_size >= required) {
        char* ws = (char*)d_ws;
        float* total = (float*)ws;
        int* offs = (int*)(ws + offs_off);
        int2* sorted = (int2*)(ws + sorted_off);

        // zero total + histogram
        hipMemsetAsync(d_ws, 0, offs_off + offs_bytes, stream);

        hist_total_kernel<<<2048, 256, 0, stream>>>(eidx, ew, n_edges, offs, total);
        scan_kernel<<<1, 1024, 0, stream>>>(offs, n_right);
        scatter_kernel<<<2048, 256, 0, stream>>>(eidx, ew, n_edges, offs, sorted);

        {
            long long n_threads = (long long)n_right * EMB;
            int blocks = (int)((n_threads + 255) / 256);
            seg_gather_kernel<<<blocks, 256, 0, stream>>>(
                sorted, offs, left, right, c, temp, total, out, n_right);
        }
        {
            int blocks = (n_right + 255) / 256;
            mlp_kernel<<<blocks, 256, 0, stream>>>(W1, b1, W2, b2, out, n_right);
        }
    } else {
        // fallback: atomic path
        float* total = (float*)d_ws;
        hipMemsetAsync(d_out, 0, (size_t)out_size * sizeof(float), stream);
        hipMemsetAsync(d_ws, 0, sizeof(float), stream);
        sum_weights_kernel<<<2048, 256, 0, stream>>>(ew, n_edges, total);
        long long n_threads = (long long)n_edges * EMB;
        long long blocks = (n_threads + 255) / 256;
        edge_scatter_kernel<<<(int)blocks, 256, 0, stream>>>(
            eidx, ew, left, total, out, n_threads);
        int mblocks = (n_right + 255) / 256;
        fused_mlp_kernel<<<mblocks, 256, 0, stream>>>(right, c, temp, W1, b1, W2,
                                                      b2, out, n_right);
    }
}

// Round 3
// 625.212 us; speedup vs baseline: 1.4188x; 1.2861x over previous
//
#include <hip/hip_runtime.h>

#define EMB 64

// bf16 helpers (manual RNE pack/unpack)
__device__ __forceinline__ unsigned short f2bf(float f) {
    unsigned u = __float_as_uint(f);
    u = u + 0x7FFFu + ((u >> 16) & 1u);
    return (unsigned short)(u >> 16);
}
__device__ __forceinline__ float bf2f(unsigned short s) {
    return __uint_as_float(((unsigned)s) << 16);
}

// K0: convert left (f32) -> left16 (bf16), 2 elems/thread
__global__ void convert_left_kernel(const float* __restrict__ left,
                                    unsigned* __restrict__ left16, int n2) {
    int i = blockIdx.x * blockDim.x + threadIdx.x;
    if (i >= n2) return;
    float2 v = ((const float2*)left)[i];
    left16[i] = (unsigned)f2bf(v.x) | ((unsigned)f2bf(v.y) << 16);
}

// K1: counts[row]++ over edges, and total = sum(edge_weight)
__global__ void hist_total_kernel(const int2* __restrict__ eidx,
                                  const float* __restrict__ w, int n_edges,
                                  int* __restrict__ counts,
                                  float* __restrict__ total) {
    int gid = blockIdx.x * blockDim.x + threadIdx.x;
    int stride = gridDim.x * blockDim.x;
    float s = 0.f;
    for (int e = gid; e < n_edges; e += stride) {
        s += w[e];
        atomicAdd(&counts[eidx[e].x], 1);
    }
    #pragma unroll
    for (int off = 32; off > 0; off >>= 1) s += __shfl_down(s, off, 64);
    if ((threadIdx.x & 63) == 0) atomicAdd(total, s);
}

// K2a: per-1024-tile inclusive scan; tile sums to bsums
__global__ __launch_bounds__(1024, 1) void scan1_kernel(
    const int* __restrict__ cnt, int* __restrict__ incl,
    int* __restrict__ bsums, int n) {
    __shared__ int s[1024];
    int t = threadIdx.x;
    int i = blockIdx.x * 1024 + t;
    int v = (i < n) ? cnt[i] : 0;
    s[t] = v;
    __syncthreads();
    for (int off = 1; off < 1024; off <<= 1) {
        int u = (t >= off) ? s[t - off] : 0;
        __syncthreads();
        s[t] += u;
        __syncthreads();
    }
    if (i < n) incl[i] = s[t];
    if (t == 1023) bsums[blockIdx.x] = s[t];
}

// K2b: exclusive scan of block sums (single block, nb <= 256)
__global__ __launch_bounds__(256, 1) void scan2_kernel(int* __restrict__ bsums, int nb) {
    __shared__ int s[256];
    int t = threadIdx.x;
    int v = (t < nb) ? bsums[t] : 0;
    s[t] = v;
    __syncthreads();
    for (int off = 1; off < 256; off <<= 1) {
        int u = (t >= off) ? s[t - off] : 0;
        __syncthreads();
        s[t] += u;
        __syncthreads();
    }
    if (t < nb) bsums[t] = s[t] - v;  // exclusive base
    __syncthreads();
}

// K2c: offs[i] = exclusive global scan = incl[i-1] + base[(i-1)>>10]
__global__ void scan3_kernel(const int* __restrict__ incl,
                             const int* __restrict__ base,
                             int* __restrict__ offs, int n) {
    int i = blockIdx.x * blockDim.x + threadIdx.x;
    if (i >= n) return;
    offs[i] = (i == 0) ? 0 : incl[i - 1] + base[(i - 1) >> 10];
}

// K3: scatter (col, w) into row-sorted order. offs[r] becomes segment END.
__global__ void scatter_kernel(const int2* __restrict__ eidx,
                               const float* __restrict__ w, int n_edges,
                               int* __restrict__ offs,
                               int2* __restrict__ sorted) {
    int gid = blockIdx.x * blockDim.x + threadIdx.x;
    int stride = gridDim.x * blockDim.x;
    for (int e = gid; e < n_edges; e += stride) {
        int2 rc = eidx[e];
        float v = w[e];
        int pos = atomicAdd(&offs[rc.x], 1);
        sorted[pos] = make_int2(rc.y, __float_as_int(v));
    }
}

// K4: one wave per row (bf16 gathers): h = right + t1*(c - conv/total)
__global__ void seg_gather_bf16_kernel(const int2* __restrict__ sorted,
                                       const int* __restrict__ offs,
                                       const unsigned short* __restrict__ left16,
                                       const float* __restrict__ right,
                                       const float* __restrict__ c,
                                       const float* __restrict__ temp,
                                       const float* __restrict__ total,
                                       float* __restrict__ hout, int n_right) {
    int gid = blockIdx.x * blockDim.x + threadIdx.x;
    int wid = gid >> 6;
    int lane = gid & 63;
    if (wid >= n_right) return;
    int end = offs[wid];
    int start = (wid == 0) ? 0 : offs[wid - 1];

    float a0 = 0.f, a1 = 0.f, a2 = 0.f, a3 = 0.f;
    int e = start;
    for (; e + 4 <= end; e += 4) {
        int2 c0 = sorted[e + 0];
        int2 c1 = sorted[e + 1];
        int2 c2 = sorted[e + 2];
        int2 c3 = sorted[e + 3];
        a0 = fmaf(__int_as_float(c0.y), bf2f(left16[(size_t)c0.x * EMB + lane]), a0);
        a1 = fmaf(__int_as_float(c1.y), bf2f(left16[(size_t)c1.x * EMB + lane]), a1);
        a2 = fmaf(__int_as_float(c2.y), bf2f(left16[(size_t)c2.x * EMB + lane]), a2);
        a3 = fmaf(__int_as_float(c3.y), bf2f(left16[(size_t)c3.x * EMB + lane]), a3);
    }
    for (; e < end; ++e) {
        int2 cc = sorted[e];
        a0 = fmaf(__int_as_float(cc.y), bf2f(left16[(size_t)cc.x * EMB + lane]), a0);
    }
    float conv = (a0 + a1) + (a2 + a3);
    float inv = 1.0f / fmaxf(total[0], 1.0f);
    float t1 = temp[1];
    float h = right[(size_t)wid * EMB + lane] + t1 * (c[wid] - conv * inv);
    hout[(size_t)wid * EMB + lane] = h;
}

// K4 variant: f32 gathers (if ws can't fit left16)
__global__ void seg_gather_f32_kernel(const int2* __restrict__ sorted,
                                      const int* __restrict__ offs,
                                      const float* __restrict__ left,
                                      const float* __restrict__ right,
                                      const float* __restrict__ c,
                                      const float* __restrict__ temp,
                                      const float* __restrict__ total,
                                      float* __restrict__ hout, int n_right) {
    int gid = blockIdx.x * blockDim.x + threadIdx.x;
    int wid = gid >> 6;
    int lane = gid & 63;
    if (wid >= n_right) return;
    int end = offs[wid];
    int start = (wid == 0) ? 0 : offs[wid - 1];
    float a0 = 0.f, a1 = 0.f, a2 = 0.f, a3 = 0.f;
    int e = start;
    for (; e + 4 <= end; e += 4) {
        int2 c0 = sorted[e + 0];
        int2 c1 = sorted[e + 1];
        int2 c2 = sorted[e + 2];
        int2 c3 = sorted[e + 3];
        a0 = fmaf(__int_as_float(c0.y), left[(size_t)c0.x * EMB + lane], a0);
        a1 = fmaf(__int_as_float(c1.y), left[(size_t)c1.x * EMB + lane], a1);
        a2 = fmaf(__int_as_float(c2.y), left[(size_t)c2.x * EMB + lane], a2);
        a3 = fmaf(__int_as_float(c3.y), left[(size_t)c3.x * EMB + lane], a3);
    }
    for (; e < end; ++e) {
        int2 cc = sorted[e];
        a0 = fmaf(__int_as_float(cc.y), left[(size_t)cc.x * EMB + lane], a0);
    }
    float conv = (a0 + a1) + (a2 + a3);
    float inv = 1.0f / fmaxf(total[0], 1.0f);
    float t1 = temp[1];
    float h = right[(size_t)wid * EMB + lane] + t1 * (c[wid] - conv * inv);
    hout[(size_t)wid * EMB + lane] = h;
}

// K5: MLP on h (in place in io): out = relu(h@W1^T+b1)@W2^T+b2
__global__ __launch_bounds__(256, 1) void mlp_kernel(
    const float* __restrict__ W1, const float* __restrict__ b1,
    const float* __restrict__ W2, const float* __restrict__ b2,
    float* __restrict__ io, int n) {
    int r = blockIdx.x * blockDim.x + threadIdx.x;
    if (r >= n) return;

    float h[EMB];
    const float4* qp = (const float4*)(io + (size_t)r * EMB);
    #pragma unroll
    for (int q = 0; q < EMB / 4; ++q) {
        float4 qv = qp[q];
        h[4 * q + 0] = qv.x;
        h[4 * q + 1] = qv.y;
        h[4 * q + 2] = qv.z;
        h[4 * q + 3] = qv.w;
    }

    float h1[EMB];
    #pragma unroll
    for (int j = 0; j < EMB; j += 4) {
        float s0 = b1[j + 0], s1 = b1[j + 1], s2 = b1[j + 2], s3 = b1[j + 3];
        #pragma unroll
        for (int k = 0; k < EMB; ++k) {
            float hk = h[k];
            s0 = fmaf(hk, W1[(j + 0) * EMB + k], s0);
            s1 = fmaf(hk, W1[(j + 1) * EMB + k], s1);
            s2 = fmaf(hk, W1[(j + 2) * EMB + k], s2);
            s3 = fmaf(hk, W1[(j + 3) * EMB + k], s3);
        }
        h1[j + 0] = fmaxf(s0, 0.f);
        h1[j + 1] = fmaxf(s1, 0.f);
        h1[j + 2] = fmaxf(s2, 0.f);
        h1[j + 3] = fmaxf(s3, 0.f);
    }

    float4* op = (float4*)(io + (size_t)r * EMB);
    #pragma unroll
    for (int j = 0; j < EMB; j += 4) {
        float s0 = b2[j + 0], s1 = b2[j + 1], s2 = b2[j + 2], s3 = b2[j + 3];
        #pragma unroll
        for (int k = 0; k < EMB; ++k) {
            float hk = h1[k];
            s0 = fmaf(hk, W2[(j + 0) * EMB + k], s0);
            s1 = fmaf(hk, W2[(j + 1) * EMB + k], s1);
            s2 = fmaf(hk, W2[(j + 2) * EMB + k], s2);
            s3 = fmaf(hk, W2[(j + 3) * EMB + k], s3);
        }
        op[j / 4] = make_float4(s0, s1, s2, s3);
    }
}

// ===================== fallback (atomic path) =====================

__global__ void sum_weights_kernel(const float* __restrict__ w, int n,
                                   float* __restrict__ total) {
    int gid = blockIdx.x * blockDim.x + threadIdx.x;
    int stride = gridDim.x * blockDim.x;
    float s = 0.f;
    for (int i = gid; i < n; i += stride) s += w[i];
    #pragma unroll
    for (int off = 32; off > 0; off >>= 1) s += __shfl_down(s, off, 64);
    if ((threadIdx.x & 63) == 0) atomicAdd(total, s);
}

__global__ void edge_scatter_kernel(const int* __restrict__ idx,
                                    const float* __restrict__ w,
                                    const float* __restrict__ left,
                                    const float* __restrict__ total,
                                    float* __restrict__ conv,
                                    long long n_threads) {
    long long gid = (long long)blockIdx.x * blockDim.x + threadIdx.x;
    if (gid >= n_threads) return;
    int e = (int)(gid >> 6);
    int d = (int)(gid & 63);
    float inv = 1.0f / fmaxf(total[0], 1.0f);
    int row = idx[2 * e];
    int col = idx[2 * e + 1];
    float v = w[e] * inv;
    float msg = left[(size_t)col * EMB + d] * v;
    atomicAdd(&conv[(size_t)row * EMB + d], msg);
}

__global__ __launch_bounds__(256, 1) void fused_mlp_kernel(
    const float* __restrict__ right, const float* __restrict__ c,
    const float* __restrict__ temp,
    const float* __restrict__ W1, const float* __restrict__ b1,
    const float* __restrict__ W2, const float* __restrict__ b2,
    float* __restrict__ io, int n) {
    int r = blockIdx.x * blockDim.x + threadIdx.x;
    if (r >= n) return;
    float t1 = temp[1];
    float cv = c[r];
    float h[EMB];
    const float4* rp = (const float4*)(right + (size_t)r * EMB);
    const float4* qp = (const float4*)(io + (size_t)r * EMB);
    #pragma unroll
    for (int q = 0; q < EMB / 4; ++q) {
        float4 rv = rp[q];
        float4 qv = qp[q];
        h[4 * q + 0] = rv.x + t1 * (cv - qv.x);
        h[4 * q + 1] = rv.y + t1 * (cv - qv.y);
        h[4 * q + 2] = rv.z + t1 * (cv - qv.z);
        h[4 * q + 3] = rv.w + t1 * (cv - qv.w);
    }
    float h1[EMB];
    #pragma unroll
    for (int j = 0; j < EMB; j += 4) {
        float s0 = b1[j], s1 = b1[j + 1], s2 = b1[j + 2], s3 = b1[j + 3];
        #pragma unroll
        for (int k = 0; k < EMB; ++k) {
            float hk = h[k];
            s0 = fmaf(hk, W1[(j + 0) * EMB + k], s0);
            s1 = fmaf(hk, W1[(j + 1) * EMB + k], s1);
            s2 = fmaf(hk, W1[(j + 2) * EMB + k], s2);
            s3 = fmaf(hk, W1[(j + 3) * EMB + k], s3);
        }
        h1[j] = fmaxf(s0, 0.f);
        h1[j + 1] = fmaxf(s1, 0.f);
        h1[j + 2] = fmaxf(s2, 0.f);
        h1[j + 3] = fmaxf(s3, 0.f);
    }
    float4* op = (float4*)(io + (size_t)r * EMB);
    #pragma unroll
    for (int j = 0; j < EMB; j += 4) {
        float s0 = b2[j], s1 = b2[j + 1], s2 = b2[j + 2], s3 = b2[j + 3];
        #pragma unroll
        for (int k = 0; k < EMB; ++k) {
            float hk = h1[k];
            s0 = fmaf(hk, W2[(j + 0) * EMB + k], s0);
            s1 = fmaf(hk, W2[(j + 1) * EMB + k], s1);
            s2 = fmaf(hk, W2[(j + 2) * EMB + k], s2);
            s3 = fmaf(hk, W2[(j + 3) * EMB + k], s3);
        }
        op[j / 4] = make_float4(s0, s1, s2, s3);
    }
}

// ===================== launch =====================

extern "C" void kernel_launch(void* const* d_in, const int* in_sizes, int n_in,
                              void* d_out, int out_size, void* d_ws, size_t ws_size,
                              hipStream_t stream) {
    const float* left   = (const float*)d_in[0];
    const int*   eidx   = (const int*)d_in[2];
    const float* ew     = (const float*)d_in[3];
    const float* right  = (const float*)d_in[4];
    const float* c      = (const float*)d_in[5];
    const float* temp   = (const float*)d_in[7];
    const float* W1     = (const float*)d_in[8];
    const float* b1     = (const float*)d_in[9];
    const float* W2     = (const float*)d_in[10];
    const float* b2     = (const float*)d_in[11];

    const int n_edges = in_sizes[3];
    const int n_right = in_sizes[4] / EMB;
    const int n_left  = in_sizes[0] / EMB;
    float* out = (float*)d_out;

    const int nblocks_scan = (n_right + 1023) / 1024;  // <= 256 assumed

    // ws layout
    size_t off_total = 0;                                   // 4B
    size_t off_offs  = 64;                                  // n_right ints
    size_t off_incl  = off_offs + ((size_t)n_right * 4 + 255 & ~(size_t)255);
    size_t off_bsum  = off_incl + ((size_t)n_right * 4 + 255 & ~(size_t)255);
    size_t off_sorted = (off_bsum + 1024 + 255) & ~(size_t)255;
    size_t off_left16 = off_sorted + ((size_t)n_edges * 8 + 255 & ~(size_t)255);
    size_t req_base = off_left16;                           // without left16
    size_t req_full = off_left16 + (size_t)n_left * EMB * 2;

    if (ws_size >= req_base && nblocks_scan <= 256) {
        char* ws = (char*)d_ws;
        float* total = (float*)(ws + off_total);
        int* offs = (int*)(ws + off_offs);
        int* incl = (int*)(ws + off_incl);
        int* bsum = (int*)(ws + off_bsum);
        int2* sorted = (int2*)(ws + off_sorted);
        bool use_bf16 = (ws_size >= req_full);

        // zero total + counts (counts live in offs buffer initially)
        hipMemsetAsync(ws, 0, off_offs + (size_t)n_right * 4, stream);

        if (use_bf16) {
            unsigned* left16 = (unsigned*)(ws + off_left16);
            int n2 = n_left * EMB / 2;
            convert_left_kernel<<<(n2 + 255) / 256, 256, 0, stream>>>(left, left16, n2);
        }

        hist_total_kernel<<<2048, 256, 0, stream>>>((const int2*)eidx, ew, n_edges,
                                                    offs, total);
        scan1_kernel<<<nblocks_scan, 1024, 0, stream>>>(offs, incl, bsum, n_right);
        scan2_kernel<<<1, 256, 0, stream>>>(bsum, nblocks_scan);
        scan3_kernel<<<(n_right + 255) / 256, 256, 0, stream>>>(incl, bsum, offs, n_right);
        scatter_kernel<<<2048, 256, 0, stream>>>((const int2*)eidx, ew, n_edges,
                                                 offs, sorted);

        {
            long long n_threads = (long long)n_right * EMB;
            int blocks = (int)((n_threads + 255) / 256);
            if (use_bf16) {
                const unsigned short* left16 = (const unsigned short*)(ws + off_left16);
                seg_gather_bf16_kernel<<<blocks, 256, 0, stream>>>(
                    sorted, offs, left16, right, c, temp, total, out, n_right);
            } else {
                seg_gather_f32_kernel<<<blocks, 256, 0, stream>>>(
                    sorted, offs, left, right, c, temp, total, out, n_right);
            }
        }
        {
            int blocks = (n_right + 255) / 256;
            mlp_kernel<<<blocks, 256, 0, stream>>>(W1, b1, W2, b2, out, n_right);
        }
    } else {
        // fallback: atomic path
        float* total = (float*)d_ws;
        hipMemsetAsync(d_out, 0, (size_t)out_size * sizeof(float), stream);
        hipMemsetAsync(d_ws, 0, sizeof(float), stream);
        sum_weights_kernel<<<2048, 256, 0, stream>>>(ew, n_edges, total);
        long long n_threads = (long long)n_edges * EMB;
        long long blocks = (n_threads + 255) / 256;
        edge_scatter_kernel<<<(int)blocks, 256, 0, stream>>>(
            eidx, ew, left, total, out, n_threads);
        int mblocks = (n_right + 255) / 256;
        fused_mlp_kernel<<<mblocks, 256, 0, stream>>>(right, c, temp, W1, b1, W2,
                                                      b2, out, n_right);
    }
}